// Round 2
// baseline (203.022 us; speedup 1.0000x reference)
//
#include <hip/hip_runtime.h>
#include <hip/hip_bf16.h>
#include <stdint.h>

// Problem constants (reference: B=2, T=2048, E=1024, H=16, D=64)
// q = x@Wq^T etc., T5 rel-pos bias, causal softmax, out = (PV)@Wo^T.

typedef __attribute__((ext_vector_type(8))) short bf16x8;   // 8 bf16 = 4 VGPR (MFMA A/B frag)
typedef __attribute__((ext_vector_type(4))) float f32x4;    // MFMA C/D frag

#define MFMA16(a, b, c) __builtin_amdgcn_mfma_f32_16x16x32_bf16((a), (b), (c), 0, 0, 0)

typedef __attribute__((address_space(1))) void gvoid_t;
typedef __attribute__((address_space(3))) void lvoid_t;

// async global->LDS, 16B per lane; lds base must be wave-uniform (HW: base + lane*16)
__device__ __forceinline__ void gload16(const void* g, void* l) {
    __builtin_amdgcn_global_load_lds((gvoid_t*)g, (lvoid_t*)l, 16, 0, 0);
}

__device__ __forceinline__ ushort f2bf_rne(float f) {
    union { float f; uint32_t u; } v; v.f = f;
    uint32_t u = v.u;
    return (ushort)((u + 0x7FFFu + ((u >> 16) & 1u)) >> 16);
}

// ---------------- fp32 -> bf16 conversion ----------------
__global__ void cvt_f2bf(const float* __restrict__ in, ushort* __restrict__ out, int n) {
    int i = (blockIdx.x * 256 + threadIdx.x) * 4;
    if (i + 3 < n) {
        float4 f = *(const float4*)(in + i);
        ushort4 o;
        o.x = f2bf_rne(f.x); o.y = f2bf_rne(f.y);
        o.z = f2bf_rne(f.z); o.w = f2bf_rne(f.w);
        *(ushort4*)(out + i) = o;
    }
}

// ---------------- T5 bias table: bias_tab[h][rel], rel in [0,2048) ----------------
// bucket thresholds derived exactly: t>=n iff rel >= ceil(8*2^(n/2)) -> {8,12,16,23,32,46,64,91}
__global__ void build_bias(const float* __restrict__ rel_emb, float* __restrict__ bias_tab) {
    int idx = blockIdx.x * 256 + threadIdx.x;       // 16*2048
    int h = idx >> 11, rel = idx & 2047;
    int bucket;
    if (rel == 0) bucket = 0;
    else if (rel < 8) bucket = 16 + rel;
    else {
        int t;
        if      (rel >= 91) t = 7;
        else if (rel >= 64) t = 6;
        else if (rel >= 46) t = 5;
        else if (rel >= 32) t = 4;
        else if (rel >= 23) t = 3;
        else if (rel >= 16) t = 2;
        else if (rel >= 12) t = 1;
        else                t = 0;
        bucket = 24 + t;                             // 16 + min(15, 8+t)
    }
    bias_tab[idx] = rel_emb[bucket * 16 + h];
}

// ---------------- GEMM: C[M=4096][N] = A[4096][1024] * W[N][1024]^T (bf16 in, fp32 acc) ----
// MODE 0: fused QKV -> writes q,k [B,H,T,D] bf16 and V TRANSPOSED [B,H,D,T] bf16
// MODE 1: out-proj -> writes fp32 d_out [4096][1024]
template<int MODE>
__global__ __launch_bounds__(256, 2) void gemm_bt(
    const ushort* __restrict__ A,
    const ushort* __restrict__ W0, const ushort* __restrict__ W1, const ushort* __restrict__ W2,
    ushort* __restrict__ outq, ushort* __restrict__ outk, ushort* __restrict__ outvt,
    float* __restrict__ outf)
{
    __shared__ __align__(16) ushort lsA[128 * 32];
    __shared__ __align__(16) ushort lsB[128 * 32];
    const int tid = threadIdx.x;
    const int lane = tid & 63, w = tid >> 6;
    const int g = lane >> 4, c16 = lane & 15;
    const int m0 = blockIdx.x * 128;
    const int wm = w >> 1, wn = w & 1;

    const ushort* W;
    int n0, widx = 0;
    if (MODE == 0) {
        widx = blockIdx.y >> 3;
        W = (widx == 0) ? W0 : (widx == 1) ? W1 : W2;
        n0 = (blockIdx.y & 7) * 128;
    } else {
        W = W0;
        n0 = blockIdx.y * 128;
    }

    f32x4 acc[4][4];
    #pragma unroll
    for (int i = 0; i < 4; i++)
        #pragma unroll
        for (int j = 0; j < 4; j++) acc[i][j] = (f32x4){0.f, 0.f, 0.f, 0.f};

    // staging chunk (16B) assignment; XOR swizzle j ^= (row>>1)&3 -> 2-way-max bank aliasing on reads
    int crow[2], cj[2];
    #pragma unroll
    for (int i = 0; i < 2; i++) {
        int c = (i * 4 + w) * 64 + lane;
        crow[i] = c >> 2;
        cj[i] = (c & 3) ^ ((crow[i] >> 1) & 3);
    }

    for (int kt = 0; kt < 1024; kt += 32) {
        #pragma unroll
        for (int i = 0; i < 2; i++) {
            gload16(A + (m0 + crow[i]) * 1024 + kt + cj[i] * 8, lsA + (i * 4 + w) * 512);
            gload16(W + (n0 + crow[i]) * 1024 + kt + cj[i] * 8, lsB + (i * 4 + w) * 512);
        }
        __syncthreads();   // drains vmcnt -> staging visible
        bf16x8 af[4], bf[4];
        #pragma unroll
        for (int mi = 0; mi < 4; mi++) {
            int row = wm * 64 + mi * 16 + c16;
            af[mi] = *(const bf16x8*)(lsA + row * 32 + ((g ^ ((row >> 1) & 3)) * 8));
        }
        #pragma unroll
        for (int ni = 0; ni < 4; ni++) {
            int row = wn * 64 + ni * 16 + c16;
            bf[ni] = *(const bf16x8*)(lsB + row * 32 + ((g ^ ((row >> 1) & 3)) * 8));
        }
        #pragma unroll
        for (int mi = 0; mi < 4; mi++)
            #pragma unroll
            for (int ni = 0; ni < 4; ni++)
                acc[mi][ni] = MFMA16(af[mi], bf[ni], acc[mi][ni]);
        __syncthreads();   // protect LDS from next-iter staging
    }

    // epilogue. C/D frag: col = lane&15, row = g*4 + r (m89-verified)
    #pragma unroll
    for (int mi = 0; mi < 4; mi++) {
        #pragma unroll
        for (int ni = 0; ni < 4; ni++) {
            int mg = m0 + wm * 64 + mi * 16 + g * 4;
            if (MODE == 0) {
                int f = n0 + wn * 64 + ni * 16 + c16;     // feature in [0,1024)
                int h = f >> 6, d = f & 63;
                if (widx < 2) {
                    ushort* dst = (widx == 0) ? outq : outk;
                    #pragma unroll
                    for (int r = 0; r < 4; r++) {
                        int m = mg + r, b = m >> 11, t = m & 2047;
                        dst[((b * 16 + h) * 2048 + t) * 64 + d] = f2bf_rne(acc[mi][ni][r]);
                    }
                } else {
                    int b = mg >> 11, t = mg & 2047;      // 4 rows stay in one b (tiles 128-aligned)
                    ushort4 pk;
                    pk.x = f2bf_rne(acc[mi][ni][0]); pk.y = f2bf_rne(acc[mi][ni][1]);
                    pk.z = f2bf_rne(acc[mi][ni][2]); pk.w = f2bf_rne(acc[mi][ni][3]);
                    *(ushort4*)(outvt + ((size_t)(b * 16 + h) * 64 + d) * 2048 + t) = pk;
                }
            } else {
                int ng = n0 + wn * 64 + ni * 16 + c16;
                #pragma unroll
                for (int r = 0; r < 4; r++) {
                    int m = mg + r;
                    outf[(size_t)m * 1024 + ng] = acc[mi][ni][r];
                }
            }
        }
    }
}

// ---------------- Flash attention (causal + T5 bias), bf16 MFMA, fp32 softmax ----------
// 64 q-rows/block, 4 waves x 16 rows. Swapped QK^T: S^T = mfma(K, Q) so softmax state is
// lane-local per q-row (col = lane&15). PV as O^T = mfma(V^T, P^T) with V stored [B,H,D,T].
__global__ __launch_bounds__(256, 2) void attn_kernel(
    const ushort* __restrict__ qb_, const ushort* __restrict__ kb_,
    const ushort* __restrict__ vtb, const float* __restrict__ bias_tab,
    ushort* __restrict__ ob)
{
    __shared__ __align__(16) ushort Qs[64 * 64];
    __shared__ __align__(16) ushort Ks[64 * 64];
    __shared__ __align__(16) ushort Vs[64 * 64];          // V^T tile: [d][kpos]
    __shared__ __align__(16) ushort Ps[4][16 * 72];       // per-wave P, padded (144B rows)

    const int tid = threadIdx.x, lane = tid & 63, w = tid >> 6;
    const int g = lane >> 4, c16 = lane & 15;
    const int bh = blockIdx.y;
    const int qb = (blockIdx.x + bh) & 31;                // work-balance swizzle (causal ramp)
    const int b = bh >> 4, h = bh & 15;

    const ushort* qh = qb_ + (size_t)bh * 2048 * 64;
    const ushort* kh = kb_ + (size_t)bh * 2048 * 64;
    const ushort* vh = vtb + (size_t)bh * 64 * 2048;
    const float* bt = bias_tab + h * 2048;
    const int q0 = qb * 64;

    int crow[2], cj[2];
    #pragma unroll
    for (int i = 0; i < 2; i++) {
        int c = (i * 4 + w) * 64 + lane;
        crow[i] = c >> 3;
        cj[i] = (c & 7) ^ (crow[i] & 7);                  // full 3-bit XOR swizzle
    }

    // stage Q tile once
    #pragma unroll
    for (int i = 0; i < 2; i++)
        gload16(qh + (q0 + crow[i]) * 64 + cj[i] * 8, Qs + (i * 4 + w) * 512);
    __syncthreads();

    bf16x8 qf[2];
    {
        int row = w * 16 + c16;
        #pragma unroll
        for (int kk = 0; kk < 2; kk++)
            qf[kk] = *(const bf16x8*)(Qs + row * 64 + (((kk * 4 + g) ^ (row & 7)) * 8));
    }
    const int qrow = q0 + w * 16 + c16;

    float m_run = -1e30f, l_run = 0.f;
    f32x4 o[4];
    #pragma unroll
    for (int ni = 0; ni < 4; ni++) o[ni] = (f32x4){0.f, 0.f, 0.f, 0.f};
    const float bias_far = bt[128];                       // bucket 31 (all rel >= 91)

    for (int j64 = 0; j64 <= qb; j64++) {
        const int k0 = j64 * 64;
        __syncthreads();                                  // prev readers done before overwrite
        #pragma unroll
        for (int i = 0; i < 2; i++) {
            gload16(kh + (k0 + crow[i]) * 64 + cj[i] * 8, Ks + (i * 4 + w) * 512);
            gload16(vh + crow[i] * 2048 + k0 + cj[i] * 8, Vs + (i * 4 + w) * 512);
        }
        __syncthreads();

        // S^T = K * Q^T  (rows = kpos, cols = q-rows)
        f32x4 s[4];
        #pragma unroll
        for (int f = 0; f < 4; f++) s[f] = (f32x4){0.f, 0.f, 0.f, 0.f};
        #pragma unroll
        for (int kk = 0; kk < 2; kk++) {
            #pragma unroll
            for (int f = 0; f < 4; f++) {
                int row = f * 16 + c16;
                bf16x8 a = *(const bf16x8*)(Ks + row * 64 + (((kk * 4 + g) ^ (row & 7)) * 8));
                s[f] = MFMA16(a, qf[kk], s[f]);
            }
        }

        // online softmax; lane holds S[kpos = k0+f*16+g*4+r][qrow]
        const bool near = (qb - j64) < 3;                 // only these need the bias table
        const bool diag = (j64 == qb);
        float p[4][4];
        float mt = -1e30f;
        #pragma unroll
        for (int f = 0; f < 4; f++) {
            #pragma unroll
            for (int r = 0; r < 4; r++) {
                int kpos = k0 + f * 16 + g * 4 + r;
                int rel = qrow - kpos;
                float lg;
                if (diag && rel < 0) lg = -1e30f;          // causal mask
                else {
                    float bias = near ? bt[rel] : bias_far;
                    lg = s[f][r] * 0.125f + bias;
                }
                p[f][r] = lg;
                mt = fmaxf(mt, lg);
            }
        }
        mt = fmaxf(mt, __shfl_xor(mt, 16));
        mt = fmaxf(mt, __shfl_xor(mt, 32));
        float m_new = fmaxf(m_run, mt);
        float alpha = __expf(m_run - m_new);
        float lt = 0.f;
        #pragma unroll
        for (int f = 0; f < 4; f++)
            #pragma unroll
            for (int r = 0; r < 4; r++) {
                float e = __expf(p[f][r] - m_new);
                p[f][r] = e;
                lt += e;
            }
        lt += __shfl_xor(lt, 16);
        lt += __shfl_xor(lt, 32);
        l_run = l_run * alpha + lt;
        m_run = m_new;
        #pragma unroll
        for (int ni = 0; ni < 4; ni++) {
            o[ni][0] *= alpha; o[ni][1] *= alpha; o[ni][2] *= alpha; o[ni][3] *= alpha;
        }

        // P -> per-wave LDS (bf16), re-read as B-operand frags (no barrier: wave-private)
        #pragma unroll
        for (int f = 0; f < 4; f++) {
            ushort4 pk;
            pk.x = f2bf_rne(p[f][0]); pk.y = f2bf_rne(p[f][1]);
            pk.z = f2bf_rne(p[f][2]); pk.w = f2bf_rne(p[f][3]);
            *(ushort4*)(&Ps[w][c16 * 72 + f * 16 + g * 4]) = pk;
        }
        #pragma unroll
        for (int kk = 0; kk < 2; kk++) {
            bf16x8 pf = *(const bf16x8*)(&Ps[w][c16 * 72 + kk * 32 + g * 8]);
            #pragma unroll
            for (int ni = 0; ni < 4; ni++) {
                int row = ni * 16 + c16;
                bf16x8 av = *(const bf16x8*)(Vs + row * 64 + (((kk * 4 + g) ^ (row & 7)) * 8));
                o[ni] = MFMA16(av, pf, o[ni]);            // O^T[d][q]
            }
        }
    }

    // normalize + write [B,T,H*D] bf16; lane: qt = c16, d = ni*16 + g*4 + r (contiguous in r)
    float inv = 1.f / l_run;
    size_t base = ((size_t)(b * 2048 + qrow)) * 1024 + h * 64;
    #pragma unroll
    for (int ni = 0; ni < 4; ni++) {
        ushort4 pk;
        pk.x = f2bf_rne(o[ni][0] * inv); pk.y = f2bf_rne(o[ni][1] * inv);
        pk.z = f2bf_rne(o[ni][2] * inv); pk.w = f2bf_rne(o[ni][3] * inv);
        *(ushort4*)(ob + base + ni * 16 + g * 4) = pk;
    }
}

// ---------------- launch ----------------
extern "C" void kernel_launch(void* const* d_in, const int* in_sizes, int n_in,
                              void* d_out, int out_size, void* d_ws, size_t ws_size,
                              hipStream_t stream) {
    const float* x       = (const float*)d_in[0];
    const float* Wq      = (const float*)d_in[1];
    const float* Wk      = (const float*)d_in[2];
    const float* Wv      = (const float*)d_in[3];
    const float* Wo      = (const float*)d_in[4];
    const float* rel_emb = (const float*)d_in[5];

    char* ws = (char*)d_ws;
    ushort* xbf = (ushort*)(ws);                       // 8 MB  [4096][1024]
    ushort* wqb = (ushort*)(ws + (8u  << 20));         // 2 MB
    ushort* wkb = (ushort*)(ws + (10u << 20));
    ushort* wvb = (ushort*)(ws + (12u << 20));
    ushort* wob = (ushort*)(ws + (14u << 20));
    ushort* qbf = (ushort*)(ws + (16u << 20));         // 8 MB  [B,H,T,D]
    ushort* kbf = (ushort*)(ws + (24u << 20));         // 8 MB  [B,H,T,D]
    ushort* vtb = (ushort*)(ws + (32u << 20));         // 8 MB  [B,H,D,T]
    ushort* obf = (ushort*)(ws + (40u << 20));         // 8 MB  [4096][1024]
    float*  btab = (float*)(ws + (48u << 20));         // 128 KB [16][2048]

    cvt_f2bf<<<4096, 256, 0, stream>>>(x,  xbf, 4194304);
    cvt_f2bf<<<1024, 256, 0, stream>>>(Wq, wqb, 1048576);
    cvt_f2bf<<<1024, 256, 0, stream>>>(Wk, wkb, 1048576);
    cvt_f2bf<<<1024, 256, 0, stream>>>(Wv, wvb, 1048576);
    cvt_f2bf<<<1024, 256, 0, stream>>>(Wo, wob, 1048576);
    build_bias<<<128, 256, 0, stream>>>(rel_emb, btab);

    gemm_bt<0><<<dim3(32, 24), 256, 0, stream>>>(xbf, wqb, wkb, wvb, qbf, kbf, vtb, nullptr);
    attn_kernel<<<dim3(32, 32), 256, 0, stream>>>(qbf, kbf, vtb, btab, obf);
    gemm_bt<1><<<dim3(32, 8), 256, 0, stream>>>(obf, wob, nullptr, nullptr,
                                                nullptr, nullptr, nullptr, (float*)d_out);
}